// Round 10
// baseline (2126.088 us; speedup 1.0000x reference)
//
#include <hip/hip_runtime.h>
#include <stdint.h>
#include <math.h>

// longformer-base-4096 forward, MI355X gfx950.
// R17: wconv v7 — write-page locality. One block owns a full 64-col n-strip
// across all K, looping K in 64-chunks with rolling register prefetch. Each
// output row's full K*2B is written by ONE block in temporally-adjacent
// 128B segments -> L2 coalesces into whole DRAM pages (v6 scattered 128B/page
// across blocks; theory: that's the 2.6 TB/s cap). Read pattern + 65-stride
// LDS transpose unchanged. Rest = R16 (gemm2 qkv/ffn1/ffn2-sk4, in-place
// o-proj EPI4, R11 attn + XCD swizzle).
#define NL 12
#define SQ 4096
#define DM 768
#define NH 12
#define DHD 64
#define FF 3072
#define WW 256

typedef unsigned short u16;
typedef __attribute__((ext_vector_type(8))) short bf8_t;   // 8 bf16 (4 VGPR)
typedef __attribute__((ext_vector_type(4))) short s16x4;   // 8B store
typedef __attribute__((ext_vector_type(4))) float f4;      // MFMA C/D

__device__ __forceinline__ float bf2f(u16 h) {
  union { unsigned int u; float f; } c; c.u = ((unsigned int)h) << 16; return c.f;
}
__device__ __forceinline__ u16 f2bf(float f) {
  union { float f; unsigned int u; } c; c.f = f; unsigned int u = c.u;
  return (u16)((u + 0x7fffu + ((u >> 16) & 1u)) >> 16);
}
__device__ __forceinline__ int iclamp(int v, int lo, int hi) {
  return v < lo ? lo : (v > hi ? hi : v);
}
__device__ __forceinline__ void gload16(const void* g, void* l) {
  __builtin_amdgcn_global_load_lds(
      (const __attribute__((address_space(1))) void*)g,
      (__attribute__((address_space(3))) void*)l, 16, 0, 0);
}

// ---------------------------------------------------------------------------
__global__ __launch_bounds__(256) void scan_kernel(const int* __restrict__ mask,
                                                   int* __restrict__ pos) {
  __shared__ int part[256];
  int tid = threadIdx.x;
  int base = tid * 16, ssum = 0;
  for (int i = 0; i < 16; ++i) ssum += mask[base + i];
  part[tid] = ssum;
  __syncthreads();
  if (tid == 0) {
    int run = 0;
    for (int i = 0; i < 256; ++i) { int t = part[i]; part[i] = run; run += t; }
  }
  __syncthreads();
  int run = part[tid];
  for (int i = 0; i < 16; ++i) {
    int m = mask[base + i];
    run += m;
    pos[base + i] = run * m + 1;
  }
}

// ---------------------------------------------------------------------------
__device__ __forceinline__ void block_ln4(int row, f4 a, bool act,
    const float* __restrict__ s, const float* __restrict__ b,
    float* __restrict__ xo, u16* __restrict__ xh, float* red, int tid) {
  float s1 = 0.f, s2 = 0.f;
  if (act) {
#pragma unroll
    for (int j = 0; j < 4; ++j) { s1 += a[j]; s2 += a[j] * a[j]; }
  }
#pragma unroll
  for (int m = 1; m < 64; m <<= 1) { s1 += __shfl_xor(s1, m); s2 += __shfl_xor(s2, m); }
  if ((tid & 63) == 0) { red[tid >> 6] = s1; red[4 + (tid >> 6)] = s2; }
  __syncthreads();
  s1 = red[0] + red[1] + red[2] + red[3];
  s2 = red[4] + red[5] + red[6] + red[7];
  float mean = s1 * (1.f / DM);
  float var = s2 * (1.f / DM) - mean * mean;
  float inv = rsqrtf(var + 1e-5f);
  if (act) {
    const f4 sv = ((const f4*)s)[tid];
    const f4 bv = ((const f4*)b)[tid];
    f4 y;
    s16x4 hh;
#pragma unroll
    for (int j = 0; j < 4; ++j) {
      y[j] = (a[j] - mean) * inv * sv[j] + bv[j];
      hh[j] = (short)f2bf(y[j]);
    }
    ((f4*)xo)[(size_t)row * 192 + tid] = y;
    *(s16x4*)&xh[(size_t)row * DM + tid * 4] = hh;
  }
}

__global__ __launch_bounds__(256) void embed_kernel(const int* __restrict__ ids,
    const int* __restrict__ pos, const float* __restrict__ we,
    const float* __restrict__ pe, const float* __restrict__ te,
    const float* __restrict__ s, const float* __restrict__ b,
    float* __restrict__ xo, u16* __restrict__ xh) {
  __shared__ float red[8];
  int row = blockIdx.x, tid = threadIdx.x;
  bool act = tid < 192;
  f4 a = { 0.f, 0.f, 0.f, 0.f };
  if (act) {
    int id = ids[row], pz = pos[row];
    const f4 wv = ((const f4*)we)[(size_t)id * 192 + tid];
    const f4 pv = ((const f4*)pe)[(size_t)pz * 192 + tid];
    const f4 tv = ((const f4*)te)[tid];
#pragma unroll
    for (int j = 0; j < 4; ++j) a[j] = wv[j] + pv[j] + tv[j];
  }
  block_ln4(row, a, act, s, b, xo, xh, red, tid);
}

// in == xo allowed (in-place): each thread reads its own row slice before
// any write to the same slice.
__global__ __launch_bounds__(256) void ln_direct_kernel(
    const float* __restrict__ in, float* __restrict__ x, u16* __restrict__ xh,
    const float* __restrict__ s, const float* __restrict__ b) {
  __shared__ float red[8];
  int row = blockIdx.x, tid = threadIdx.x;
  bool act = tid < 192;
  f4 a = { 0.f, 0.f, 0.f, 0.f };
  if (act) a = ((const f4*)in)[(size_t)row * 192 + tid];
  block_ln4(row, a, act, s, b, x, xh, red, tid);
}

__global__ __launch_bounds__(256) void ln_fuse_kernel(
    const float* __restrict__ pp, int nparts, const float* __restrict__ bias,
    float* __restrict__ x, u16* __restrict__ xh,
    const float* __restrict__ s, const float* __restrict__ b) {
  __shared__ float red[8];
  int row = blockIdx.x, tid = threadIdx.x;
  bool act = tid < 192;
  f4 a = { 0.f, 0.f, 0.f, 0.f };
  if (act) {
    size_t i4 = (size_t)row * 192 + tid;
    a = ((const f4*)x)[i4];
    const f4 bb = ((const f4*)bias)[tid];
#pragma unroll
    for (int j = 0; j < 4; ++j) a[j] += bb[j];
    for (int p = 0; p < nparts; ++p) {
      const f4 pv = ((const f4*)pp)[(size_t)p * SQ * 192 + i4];
#pragma unroll
      for (int j = 0; j < 4; ++j) a[j] += pv[j];
    }
  }
  block_ln4(row, a, act, s, b, x, xh, red, tid);
}

// ---------------------------------------------------------------------------
// wconv v7: one block = full-K 64-col n-strip; loop K in 64-chunks with
// rolling register prefetch. Output rows written contiguously in time.
// grid (108, NL): b<36 qkv (3x12 strips), <48 wo, <96 w1 (48 strips), else w2.
__global__ __launch_bounds__(256) void wconv_all(
    const float* __restrict__ wq, const float* __restrict__ wk,
    const float* __restrict__ wv, const float* __restrict__ wo,
    const float* __restrict__ w1, const float* __restrict__ w2,
    u16* __restrict__ Wqkv, u16* __restrict__ Wo,
    u16* __restrict__ W1, u16* __restrict__ W2) {
  __shared__ float t[64 * 65];
  int b = blockIdx.x;
  int lay = blockIdx.y;
  const float* src;
  u16* dst;
  int K, N, rowoff, strip;
  if (b < 36) {
    int j = b / 12;
    strip = b - j * 12;
    src = ((j == 0) ? wq : ((j == 1) ? wk : wv)) + (size_t)lay * DM * DM;
    dst = Wqkv + (size_t)lay * 3 * DM * DM;
    K = DM; N = DM; rowoff = j * DM;
  } else if (b < 48) {
    strip = b - 36;
    src = wo + (size_t)lay * DM * DM; dst = Wo + (size_t)lay * DM * DM;
    K = DM; N = DM; rowoff = 0;
  } else if (b < 96) {
    strip = b - 48;
    src = w1 + (size_t)lay * DM * FF; dst = W1 + (size_t)lay * DM * FF;
    K = DM; N = FF; rowoff = 0;
  } else {
    strip = b - 96;
    src = w2 + (size_t)lay * FF * DM; dst = W2 + (size_t)lay * FF * DM;
    K = FF; N = DM; rowoff = 0;
  }
  const int nchunks = K >> 6;
  const int n0 = strip * 64;
  const int tid = threadIdx.x;
  const int q = tid & 15, kr = tid >> 4;   // load role: 16 lanes x f4 per row
  const int n = tid >> 4, kq = (tid & 15) * 4;  // store role

  f4 v[4];
#pragma unroll
  for (int p = 0; p < 4; ++p)
    v[p] = *(const f4*)&src[(size_t)(kr + p * 16) * N + n0 + q * 4];

  for (int kc = 0; kc < nchunks; ++kc) {
    const int k0 = kc * 64;
    f4 vn[4];
    if (kc + 1 < nchunks) {
      const int kb2 = k0 + 64;
#pragma unroll
      for (int p = 0; p < 4; ++p)
        vn[p] = *(const f4*)&src[(size_t)(kb2 + kr + p * 16) * N + n0 + q * 4];
    }
    // LDS transpose of current chunk (waits only on v, vn stays in flight)
#pragma unroll
    for (int p = 0; p < 4; ++p) {
      int k = kr + p * 16;
#pragma unroll
      for (int j = 0; j < 4; ++j) t[k * 65 + q * 4 + j] = v[p][j];
    }
    __syncthreads();
#pragma unroll
    for (int c = 0; c < 4; ++c) {
      int nn = n + c * 16;
      s16x4 st;
#pragma unroll
      for (int i = 0; i < 4; ++i)
        st[i] = (short)f2bf(t[(kq + i) * 65 + nn]);
      *(s16x4*)&dst[(size_t)(rowoff + n0 + nn) * K + k0 + kq] = st;
    }
    __syncthreads();
    if (kc + 1 < nchunks) {
#pragma unroll
      for (int p = 0; p < 4; ++p) v[p] = vn[p];
    }
  }
}

// ---------------------------------------------------------------------------
// bf16 GEMM, 128x64 tile, BK=64, 4 waves (2x2, each 64x32), 3 blocks/CU.
// EPI 3: f32 partial; EPI 4: in-place +bias+resid (outf read-modify-write).
template <int EPI>
__global__ __launch_bounds__(256, 3) void gemm1(
    const u16* __restrict__ A, const u16* __restrict__ B, int Kld, int ksl,
    int nx, int ntiles,
    const float* __restrict__ bias0,
    float* __restrict__ outf) {
  __shared__ __align__(16) char smem[49152];

  const int tid = threadIdx.x;
  const int l = tid & 63;
  const int w = tid >> 6;
  const int lr = l & 15;
  const int lg = l >> 4;
  const int nwg = gridDim.x;
  const int bid = blockIdx.x;
  const int wg = (bid & 7) * (nwg >> 3) + (bid >> 3);
  const int part = wg / ntiles;
  const int t = wg - part * ntiles;
  const int bm = (t / nx) * 128;
  const int bn = (t % nx) * 64;
  const int k0 = part * ksl;
  const int wr = (w >> 1) * 64;
  const int wc = (w & 1) * 32;

  f4 acc[4][2];
  f4 z = { 0.f, 0.f, 0.f, 0.f };
#pragma unroll
  for (int i = 0; i < 4; ++i)
#pragma unroll
    for (int j = 0; j < 2; ++j) acc[i][j] = z;

  const int srow = tid >> 3;                            // 32 rows / stage call
  const int scol = ((tid & 7) * 8) ^ ((srow & 7) * 8);  // pre-swizzled source
  const int xw = (lr & 7) * 8;                          // read-side XOR

  const int nkt = ksl >> 6;

  auto stage = [&](int slot, int kt) {
    int ksrc = k0 + (kt << 6);
    char* la = smem + slot * 24576 + (size_t)(tid & ~63) * 16;
    char* lb = la + 16384;
#pragma unroll
    for (int r = 0; r < 4; ++r)
      gload16(A + (size_t)(bm + srow + r * 32) * Kld + ksrc + scol, la + r * 4096);
#pragma unroll
    for (int r = 0; r < 2; ++r)
      gload16(B + (size_t)(bn + srow + r * 32) * Kld + ksrc + scol, lb + r * 4096);
  };

  stage(0, 0);
  stage(1, 1);
  asm volatile("s_waitcnt vmcnt(6)" ::: "memory");
  __builtin_amdgcn_s_barrier();
  __builtin_amdgcn_sched_barrier(0);

  for (int kt = 0; kt < nkt; ++kt) {
    const int cur = kt & 1;
    const u16* sA = (const u16*)(smem + cur * 24576);
    const u16* sB = sA + 8192;
#pragma unroll
    for (int ks = 0; ks < 2; ++ks) {
      bf8_t af[4], bfr[2];
#pragma unroll
      for (int mt = 0; mt < 4; ++mt)
        af[mt] = *(const bf8_t*)&sA[(wr + mt * 16 + lr) * 64 + ((ks * 32 + lg * 8) ^ xw)];
#pragma unroll
      for (int nt = 0; nt < 2; ++nt)
        bfr[nt] = *(const bf8_t*)&sB[(wc + nt * 16 + lr) * 64 + ((ks * 32 + lg * 8) ^ xw)];
#pragma unroll
      for (int mt = 0; mt < 4; ++mt)
#pragma unroll
        for (int nt = 0; nt < 2; ++nt)
          acc[mt][nt] = __builtin_amdgcn_mfma_f32_16x16x32_bf16(af[mt], bfr[nt], acc[mt][nt], 0, 0, 0);
    }
    asm volatile("s_waitcnt lgkmcnt(0)" ::: "memory");
    __builtin_amdgcn_sched_barrier(0);
    __builtin_amdgcn_s_barrier();  // block-wide reads of slot cur done
    if (kt + 2 < nkt) {
      stage(cur, kt + 2);
      asm volatile("s_waitcnt vmcnt(6)" ::: "memory");  // tile kt+1 landed
    } else {
      asm volatile("s_waitcnt vmcnt(0)" ::: "memory");
    }
    __builtin_amdgcn_s_barrier();  // publish tile kt+1
    __builtin_amdgcn_sched_barrier(0);
  }
  __syncthreads();

#pragma unroll
  for (int mt = 0; mt < 4; ++mt)
#pragma unroll
    for (int nt = 0; nt < 2; ++nt) {
      int colg = bn + wc + nt * 16 + lr;
#pragma unroll
      for (int r = 0; r < 4; ++r) {
        int rowg = bm + wr + mt * 16 + lg * 4 + r;
        size_t idx = (size_t)rowg * DM + colg;
        if constexpr (EPI == 3) {
          outf[(size_t)part * SQ * DM + idx] = acc[mt][nt][r];
        } else {
          // in-place: x[idx] = gemm + bias + x[idx]; each idx owned by one
          // thread, read precedes write on the same address.
          outf[idx] = acc[mt][nt][r] + bias0[colg] + outf[idx];
        }
      }
    }
}

// ---------------------------------------------------------------------------
// gemm2: m97-style 128x128 tile, BK=64, single-buffered 32KB LDS,
// 2 barriers/kt, 4 waves (2x2, each 64x64, acc[4][4]), 3 blocks/CU.
// EPI 0: qkv scatter; EPI 2: gelu->bf16; EPI 3: f32 split-K partial.
template <int EPI>
__global__ __launch_bounds__(256, 3) void gemm2(
    const u16* __restrict__ A, const u16* __restrict__ B, int Kld, int ksl,
    int nx, int ntiles,
    const float* __restrict__ bias0, const float* __restrict__ bias1,
    const float* __restrict__ bias2,
    u16* __restrict__ oh, u16* __restrict__ Qb, u16* __restrict__ Kb,
    u16* __restrict__ VTb, float* __restrict__ outf) {
  // K-loop: A 16KB + B 16KB = 32KB. Epilogue repack: 4 waves x 9216B = 36KB.
  __shared__ __align__(16) char smem[36864];

  const int tid = threadIdx.x;
  const int l = tid & 63;
  const int w = tid >> 6;
  const int lr = l & 15;
  const int lg = l >> 4;
  const int nwg = gridDim.x;
  const int bid = blockIdx.x;
  const int wg = (bid & 7) * (nwg >> 3) + (bid >> 3);
  const int part = wg / ntiles;
  const int t = wg - part * ntiles;
  const int bm = (t / nx) * 128;
  const int bn = (t % nx) * 128;
  const int k0 = part * ksl;
  const int wr = (w >> 1) * 64;
  const int wc = (w & 1) * 64;

  f4 acc[4][4];
  f4 z = { 0.f, 0.f, 0.f, 0.f };
#pragma unroll
  for (int i = 0; i < 4; ++i)
#pragma unroll
    for (int j = 0; j < 4; ++j) acc[i][j] = z;

  const int srow = tid >> 3;                            // 32 rows / stage call
  const int scol = ((tid & 7) * 8) ^ ((srow & 7) * 8);  // pre-swizzled source
  const int xw = (lr & 7) * 8;                          // read-side XOR

  const int nkt = ksl >> 6;

  auto stage = [&](int kt) {
    int ksrc = k0 + (kt << 6);
    char* la = smem + (size_t)(tid & ~63) * 16;
    char* lb = la + 16384;
#pragma unroll
    for (int r = 0; r < 4; ++r)
      gload16(A + (size_t)(bm + srow + r * 32) * Kld + ksrc + scol, la + r * 4096);
#pragma unroll
    for (int r = 0; r < 4; ++r)
      gload16(B + (size_t)(bn + srow + r * 32) * Kld + ksrc + scol, lb + r * 4096);
  };

  stage(0);
  for (int kt = 0; kt < nkt; ++kt) {
    asm volatile("s_waitcnt vmcnt(0)" ::: "memory");
    __builtin_amdgcn_s_barrier();          // staged tile visible to all waves
    __builtin_amdgcn_sched_barrier(0);
    const u16* sA = (const u16*)smem;
    const u16* sB = sA + 8192;
#pragma unroll
    for (int ks = 0; ks < 2; ++ks) {
      bf8_t af[4], bfr[4];
#pragma unroll
      for (int mt = 0; mt < 4; ++mt)
        af[mt] = *(const bf8_t*)&sA[(wr + mt * 16 + lr) * 64 + ((ks * 32 + lg * 8) ^ xw)];
#pragma unroll
      for (int nt = 0; nt < 4; ++nt)
        bfr[nt] = *(const bf8_t*)&sB[(wc + nt * 16 + lr) * 64 + ((ks * 32 + lg * 8) ^ xw)];
#pragma unroll
      for (int mt = 0; mt < 4; ++mt)
#pragma unroll
        for (int nt = 0; nt < 4; ++nt)
          acc[mt][nt] = __builtin_amdgcn_mfma_f32_16x16x32_bf16(af[mt], bfr[nt], acc[mt][nt], 0, 0, 0);
    }
    asm volatile("s_waitcnt lgkmcnt(0)" ::: "memory");
    __builtin_amdgcn_sched_barrier(0);
    __builtin_amdgcn_s_barrier();          // all reads done; buffer reusable
    if (kt + 1 < nkt) stage(kt + 1);       // overlaps other blocks' compute
  }

  if constexpr (EPI == 3) {
    // direct f32 split-K partial stores (no repack)
#pragma unroll
    for (int mt = 0; mt < 4; ++mt)
#pragma unroll
      for (int nt = 0; nt < 4; ++nt) {
        int colg = bn + wc + nt * 16 + lr;
#pragma unroll
        for (int r = 0; r < 4; ++r) {
          int rowg = bm + wr + mt * 16 + lg * 4 + r;
          outf[(size_t)part * SQ * DM + (size_t)rowg * DM + colg] = acc[mt][nt][r];
        }
      }
    return;
  }

  // ---- epilogues. Per-wave LDS [64][36] f32, two 32-col half-passes.
  float* ep = (float*)(smem + w * 9216);
  const int nbase = bn + wc;               // multiple of 64

  if constexpr (EPI == 0) {
    int tgt = nbase / DM;                  // 0=q 1=k 2=v (64-granules don't straddle)
    int within = nbase - tgt * DM;         // multiple of 64
    int head = within >> 6;
    const float* bp = (tgt == 0) ? bias0 : ((tgt == 1) ? bias1 : bias2);
    if (tgt == 2) {
      // direct from acc -> VT[H][DH][S]
#pragma unroll
      for (int mt = 0; mt < 4; ++mt)
#pragma unroll
        for (int nt = 0; nt < 4; ++nt) {
          int dh = nt * 16 + lr;
          float bb = bp[within + dh];
          int s0 = bm + wr + mt * 16 + lg * 4;
          s16x4 st;
#pragma unroll
          for (int r = 0; r < 4; ++r) st[r] = (short)f2bf(acc[mt][nt][r] + bb);
          *(s16x4*)&VTb[((size_t)(head * DHD + dh)) * SQ + s0] = st;
        }
    } else {
      u16* dst = (tgt == 0) ? Qb : Kb;
      float scale = (tgt == 0) ? 0.125f : 1.0f;
      int coloff = (l & 7) * 4;
#pragma unroll
      for (int half = 0; half < 2; ++half) {
        if (half) asm volatile("s_waitcnt lgkmcnt(0)" ::: "memory");
#pragma unroll
        for (int mt = 0; mt < 4; ++mt)
#pragma unroll
          for (int n2 = 0; n2 < 2; ++n2)
#pragma unroll
            for (int r = 0; r < 4; ++r)
              ep[(mt * 16 + lg * 4 + r) * 36 + n2 * 16 + lr] = acc[mt][half * 2 + n2][r];
        asm volatile("s_waitcnt lgkmcnt(0)" ::: "memory");
#pragma unroll
        for (int i = 0; i < 8; ++i) {
          int row = (l >> 3) + i * 8;
          int gs = bm + wr + row;
          f4 v = *(f4*)&ep[row * 36 + coloff];
          s16x4 st;
#pragma unroll
          for (int j = 0; j < 4; ++j)
            st[j] = (short)f2bf((v[j] + bp[within + half * 32 + coloff + j]) * scale);
          *(s16x4*)&dst[((size_t)head * SQ + gs) * DHD + half * 32 + coloff] = st;
        }
      }
    }
  } else {  // EPI == 2: gelu -> bf16 [S][FF]
    int coloff = (l & 7) * 4;
#pragma unroll
    for (int half = 0; half < 2; ++half) {
      if (half) asm volatile("s_waitcnt lgkmcnt(0)" ::: "memory");
#pragma unroll
      for (int mt = 0; mt < 4; ++mt)
#pragma unroll
        for (int n2 = 0; n2 < 2; ++n2)
#pragma unroll
          for (int r = 0; r < 4; ++r)
            ep[(mt * 16 + lg * 4 + r) * 36 + n2 * 16 + lr] = acc[mt][half * 2 + n2][r];
      asm volatile("s_waitcnt lgkmcnt(0)" ::: "memory");
#pragma unroll
      for (int i = 0; i < 8; ++i) {
        int row = (l >> 3) + i * 8;
        int gs = bm + wr + row;
        f4 v = *(f4*)&ep[row * 36 + coloff];
        s16x4 hi;
#pragma unroll
        for (int j = 0; j < 4; ++j) {
          float t2 = v[j] + bias0[nbase + half * 32 + coloff + j];
          t2 = 0.5f * t2 * (1.f + erff(t2 * 0.70710678118654752f));  // exact gelu
          hi[j] = (short)f2bf(t2);
        }
        *(s16x4*)&oh[(size_t)gs * FF + nbase + half * 32 + coloff] = hi;
      }
    }
  }
}

// ---------------------------------------------------------------------------
// sliding-window attention (R11 structure): 2 waves/block, each wave owns 32
// queries end-to-end (independent online softmax, no merge). grid (SQ/64, NH).
// XCD swizzle — 768 blocks = 8 XCDs x 96 ids.
__global__ __launch_bounds__(128) void attn_kernel(
    const u16* __restrict__ Qb, const u16* __restrict__ Kb,
    const u16* __restrict__ VTb, const int* __restrict__ mask,
    u16* __restrict__ ah) {
  __shared__ __align__(16) u16 Pl[2][32 * 72];
  __shared__ float mwin[640];
  const int tid = threadIdx.x;
  const int w = tid >> 6;          // wave id 0/1
  const int l = tid & 63;
  const int lr = l & 15, lg = l >> 4;
  // XCD swizzle: dispatch index lin -> id so each XCD gets 96 consecutive ids
  const int lin = blockIdx.y * 64 + blockIdx.x;       // == dispatch order
  const int id = (lin & 7) * 96 + (lin >> 3);         // bijective, 768 = 8*96
  const int h = id >> 6;
  const int q0 = (id & 63) * 64;
  const int qw = q0 + w * 32;      // this wave's first query
  const int kbw = qw - 256;        // this wave's key-window base
  for (int i = tid; i < 640; i += 128) {
    int kg = q0 - 256 + i;
    mwin[i] = (kg >= 0 && kg < SQ && mask[kg] != 0) ? 1.f : 0.f;
  }
  __syncthreads();
  u16* Plw = Pl[w];

  bf8_t qf[2][2];
#pragma unroll
  for (int mt = 0; mt < 2; ++mt)
#pragma unroll
    for (int ks = 0; ks < 2; ++ks)
      qf[mt][ks] = *(const bf8_t*)&Qb[((size_t)h * SQ + qw + mt * 16 + lr) * DHD + ks * 32 + lg * 8];

  f4 o[2][4];
  f4 z = { 0.f, 0.f, 0.f, 0.f };
  float mrow[2][4], lrow[2][4];
#pragma unroll
  for (int mt = 0; mt < 2; ++mt)
#pragma unroll
    for (int nt = 0; nt < 4; ++nt) o[mt][nt] = z;
#pragma unroll
  for (int mt = 0; mt < 2; ++mt)
#pragma unroll
    for (int r = 0; r < 4; ++r) { mrow[mt][r] = -1e30f; lrow[mt][r] = 0.f; }

  for (int kc = 0; kc < 9; ++kc) {
    int klb = kc * 64;             // wave-relative chunk base
    int mo = w * 32 + klb;         // block-mwin offset of this chunk
    f4 sc[2][4];
#pragma unroll
    for (int mt = 0; mt < 2; ++mt)
#pragma unroll
      for (int nt = 0; nt < 4; ++nt) sc[mt][nt] = z;
#pragma unroll
    for (int ks = 0; ks < 2; ++ks) {
      bf8_t kf[4];
#pragma unroll
      for (int nt = 0; nt < 4; ++nt) {
        int krow = iclamp(kbw + klb + nt * 16 + lr, 0, SQ - 1);
        kf[nt] = *(const bf8_t*)&Kb[((size_t)h * SQ + krow) * DHD + ks * 32 + lg * 8];
      }
#pragma unroll
      for (int mt = 0; mt < 2; ++mt)
#pragma unroll
        for (int nt = 0; nt < 4; ++nt)
          sc[mt][nt] = __builtin_amdgcn_mfma_f32_16x16x32_bf16(qf[mt][ks], kf[nt], sc[mt][nt], 0, 0, 0);
    }
    bool edge = (kc == 0) | (kc == 8);
    // interior chunks fully in-band; only key validity can mask.
    unsigned long long vb = __ballot(mwin[mo + l] > 0.5f);
    if (edge || vb != ~0ull) {
#pragma unroll
      for (int mt = 0; mt < 2; ++mt)
#pragma unroll
        for (int nt = 0; nt < 4; ++nt) {
          int col = nt * 16 + lr;
          int kg = kbw + klb + col;
          float mk = mwin[mo + col];
#pragma unroll
          for (int r = 0; r < 4; ++r) {
            int qg = qw + mt * 16 + lg * 4 + r;
            int d = kg - qg;
            bool ok = (mk > 0.5f) && (!edge || ((d <= WW) && (d >= -WW)));
            sc[mt][nt][r] = ok ? sc[mt][nt][r] : -3.0e38f;
          }
        }
    }
#pragma unroll
    for (int mt = 0; mt < 2; ++mt)
#pragma unroll
      for (int r = 0; r < 4; ++r) {
        float cm = fmaxf(fmaxf(sc[mt][0][r], sc[mt][1][r]),
                         fmaxf(sc[mt][2][r], sc[mt][3][r]));
#pragma unroll
        for (int m2 = 1; m2 < 16; m2 <<= 1) cm = fmaxf(cm, __shfl_xor(cm, m2));
        float mn = fmaxf(fmaxf(mrow[mt][r], cm), -1e30f);
        float scl = __expf(mrow[mt][r] - mn);
        mrow[mt][r] = mn;
        float ps = 0.f;
#pragma unroll
        for (int nt = 0; nt < 4; ++nt) {
          float pv = __expf(sc[mt][nt][r] - mn);
          sc[mt][nt][r] = pv;
          ps += pv;
        }
#pragma unroll
        for (int m2 = 1; m2 < 16; m2 <<= 1) ps += __shfl_xor(ps, m2);
        lrow[mt][r] = lrow[mt][r] * scl + ps;
#pragma unroll
        for (int nt = 0; nt < 4; ++nt) o[mt][nt][r] *= scl;
#pragma unroll
        for (int nt = 0; nt < 4; ++nt)
          Plw[(mt * 16 + lg * 4 + r) * 72 + nt * 16 + lr] = f2bf(sc[mt][nt][r]);
      }
    asm volatile("s_waitcnt lgkmcnt(0)" ::: "memory");
#pragma unroll
    for (int ks = 0; ks < 2; ++ks) {
      bf8_t pa[2], vf[4];
#pragma unroll
      for (int mt = 0; mt < 2; ++mt)
        pa[mt] = *(const bf8_t*)&Plw[(mt * 16 + lr) * 72 + ks * 32 + lg * 8];
      int kbase = iclamp(kbw + klb + ks * 32 + lg * 8, 0, SQ - 8);
#pragma unroll
      for (int nt = 0; nt < 4; ++nt)
        vf[nt] = *(const bf8_t*)&VTb[((size_t)h * DHD + nt * 16 + lr) * SQ + kbase];
#pragma unroll
      for (int mt = 0; mt < 2; ++mt)
#pragma unroll
        for (int nt = 0; nt < 4; ++nt)
          o[mt][nt] = __builtin_amdgcn_mfma_f32_16x16x32_bf16(pa[mt], vf[nt], o[mt][nt], 0, 0, 0);
    }
  }
#pragma unroll
  for (int mt = 0; mt < 2; ++mt)
#pragma unroll
    for (int nt = 0; nt < 4; ++nt) {
      int col = h * DHD + nt * 16 + lr;
#pragma unroll
      for (int r = 0; r < 4; ++r) {
        int gq = qw + mt * 16 + lg * 4 + r;
        float v = o[mt][nt][r] / lrow[mt][r];
        ah[(size_t)gq * DM + col] = f2bf(v);
      }
    }
}

// ---------------------------------------------------------------------------
__global__ __launch_bounds__(256) void head1_kernel(const float* __restrict__ x,
    const float* __restrict__ wp, const float* __restrict__ bp,
    float* __restrict__ y) {
  __shared__ float x0[DM];
  __shared__ float part[4][64];
  int tid = threadIdx.x;
  int w = tid >> 6, l = tid & 63;
  for (int i = tid; i < DM; i += 256) x0[i] = x[i];
  __syncthreads();
  int j = blockIdx.x * 64 + l;
  float a = 0.f;
  int i0 = w * 192;
#pragma unroll 4
  for (int i = i0; i < i0 + 192; ++i) a += x0[i] * wp[(size_t)i * DM + j];
  part[w][l] = a;
  __syncthreads();
  if (w == 0) {
    float t = part[0][l] + part[1][l] + part[2][l] + part[3][l] + bp[j];
    y[j] = tanhf(t);
  }
}

__global__ __launch_bounds__(64) void head2_kernel(const float* __restrict__ y,
    const float* __restrict__ wc, const float* __restrict__ bc,
    float* __restrict__ out) {
  int l = threadIdx.x;
  float acc[6] = {0.f, 0.f, 0.f, 0.f, 0.f, 0.f};
  for (int i = l; i < DM; i += 64) {
    float yv = y[i];
#pragma unroll
    for (int j = 0; j < 6; ++j) acc[j] += yv * wc[i * 6 + j];
  }
#pragma unroll
  for (int j = 0; j < 6; ++j)
#pragma unroll
    for (int m = 1; m < 64; m <<= 1) acc[j] += __shfl_xor(acc[j], m);
  if (l == 0) {
#pragma unroll
    for (int j = 0; j < 6; ++j) out[j] = acc[j] + bc[j];
  }
}

// ---------------------------------------------------------------------------
extern "C" void kernel_launch(void* const* d_in, const int* in_sizes, int n_in,
                              void* d_out, int out_size, void* d_ws, size_t ws_size,
                              hipStream_t stream) {
  const int* ids = (const int*)d_in[0];
  const int* mask = (const int*)d_in[1];
  const float* we = (const float*)d_in[2];
  const float* pe = (const float*)d_in[3];
  const float* te = (const float*)d_in[4];
  const float* ln_e_s = (const float*)d_in[5];
  const float* ln_e_b = (const float*)d_in[6];
  const float* wq = (const float*)d_in[7];
  const float* bq = (const float*)d_in[8];
  const float* wk = (const float*)d_in[9];
  const float* bk = (const float*)d_in[10];
  const float* wv = (const float*)d_in[11];
  const float* bv = (const float*)d_in[12];
  const float* wo = (const float*)d_in[13];
  const float* bo = (const float*)d_in[14];
  const float* ln1_s = (const float*)d_in[15];
  const float* ln1_b = (const float*)d_in[16];
  const float* w1 = (const float*)d_in[17];
  const float* b1 = (const float*)d_in[18];
  const float* w2 = (const float*)d_in[19];
  const float* b2 = (const float*)d_in[20];
  const float* ln2_s = (const float*)d_in[21];
  const float* ln2_b = (const float*)d_in[22];
  const float* wpool = (const float*)d_in[23];
  const float* bpool = (const float*)d_in[24];
  const float* wcls = (const float*)d_in[25];
  const float* bcls = (const float*)d_in[26];

  char* p = (char*)d_ws;
  auto take = [&](size_t bytes) {
    char* r = p;
    p += (bytes + 255) & ~(size_t)255;
    return r;
  };
  int* pos = (int*)take((size_t)SQ * 4);
  float* x = (float*)take((size_t)SQ * DM * 4);
  float* pp = (float*)take((size_t)4 * SQ * DM * 4);  // split-K partials (<=4)
  u16* xh = (u16*)take((size_t)SQ * DM * 2);
  u16* Wqkv_h = (u16*)take((size_t)NL * 3 * DM * DM * 2);
  u16* Wo_h = (u16*)take((size_t)NL * DM * DM * 2);
  u16* W1_h = (u16*)take((size_t)NL * DM * FF * 2);
  u16* W2_h = (u16*)take((size_t)NL * FF * DM * 2);
  u16* Qb = (u16*)take((size_t)NH * SQ * DHD * 2);
  u16* Kbf = (u16*)take((size_t)NH * SQ * DHD * 2);
  u16* VTb = (u16*)take((size_t)NH * DHD * SQ * 2);
  u16* ah_ = (u16*)take((size_t)SQ * DM * 2);
  u16* hh = (u16*)take((size_t)SQ * FF * 2);
  float* ypool = (float*)take((size_t)DM * 4);

  scan_kernel<<<dim3(1), dim3(256), 0, stream>>>(mask, pos);
  embed_kernel<<<dim3(SQ), dim3(256), 0, stream>>>(ids, pos, we, pe, te, ln_e_s, ln_e_b, x, xh);
  wconv_all<<<dim3(108, NL), dim3(256), 0, stream>>>(
      wq, wk, wv, wo, w1, w2, Wqkv_h, Wo_h, W1_h, W2_h);

  for (int l = 0; l < NL; ++l) {
    const u16* Wq_l = Wqkv_h + (size_t)l * 3 * DM * DM;
    const u16* Wo_l = Wo_h + (size_t)l * DM * DM;
    const u16* W1_l = W1_h + (size_t)l * DM * FF;
    const u16* W2_l = W2_h + (size_t)l * FF * DM;

    // qkv: M=4096 N=2304 K=768, 128x128 tile -> 32x18 = 576 blocks
    gemm2<0><<<dim3(576), dim3(256), 0, stream>>>(
        xh, Wq_l, DM, DM, 18, 576, bq + (size_t)l * DM, bk + (size_t)l * DM,
        bv + (size_t)l * DM, nullptr, Qb, Kbf, VTb, nullptr);
    attn_kernel<<<dim3(SQ / 64, NH), dim3(128), 0, stream>>>(Qb, Kbf, VTb, mask, ah_);
    // o-proj: M=4096 N=768 K=768, 128x64 tile, in-place x += gemm+bias
    gemm1<4><<<dim3(384), dim3(256), 0, stream>>>(
        ah_, Wo_l, DM, DM, 12, 384, bo + (size_t)l * DM, x);
    ln_direct_kernel<<<dim3(SQ), dim3(256), 0, stream>>>(
        x, x, xh, ln1_s + (size_t)l * DM, ln1_b + (size_t)l * DM);
    // ffn1: M=4096 N=3072 K=768, 128x128 tile -> 32x24 = 768 blocks (1 pass)
    gemm2<2><<<dim3(768), dim3(256), 0, stream>>>(
        xh, W1_l, DM, DM, 24, 768, b1 + (size_t)l * FF, nullptr, nullptr,
        hh, nullptr, nullptr, nullptr, nullptr);
    // ffn2: M=4096 N=768 K=3072, 128x128 tile, split-K 4 -> 192x4 = 768
    // blocks of 12 kt (exactly 1.0 pass)
    gemm2<3><<<dim3(768), dim3(256), 0, stream>>>(
        hh, W2_l, FF, FF / 4, 6, 192, nullptr, nullptr, nullptr,
        nullptr, nullptr, nullptr, nullptr, pp);
    ln_fuse_kernel<<<dim3(SQ), dim3(256), 0, stream>>>(
        pp, 4, b2 + (size_t)l * DM, x, xh, ln2_s + (size_t)l * DM, ln2_b + (size_t)l * DM);
  }

  head1_kernel<<<dim3(12), dim3(256), 0, stream>>>(x, wpool, bpool, ypool);
  head2_kernel<<<dim3(1), dim3(64), 0, stream>>>(ypool, wcls, bcls, (float*)d_out);
}

// Round 11
// 2089.180 us; speedup vs baseline: 1.0177x; 1.0177x over previous
//
#include <hip/hip_runtime.h>
#include <stdint.h>
#include <math.h>

// longformer-base-4096 forward, MI355X gfx950.
// R18: pure revert of R17's wconv v7 (write-locality theory refuted: occupancy
// 77->36%, load-imbalanced tail, 130->151us). wconv back to v6 (864x12 grid,
// 128Kx64N per block, reg-parked second sub-tile). Everything else = R16:
// gemm2 qkv/ffn1/ffn2-splitK4 (128x128 single-buffer), gemm1 o-proj EPI4
// in-place, R11 2-wave attn + ballot skip + XCD swizzle. Best measured
// configuration (~2112us).
#define NL 12
#define SQ 4096
#define DM 768
#define NH 12
#define DHD 64
#define FF 3072
#define WW 256

typedef unsigned short u16;
typedef __attribute__((ext_vector_type(8))) short bf8_t;   // 8 bf16 (4 VGPR)
typedef __attribute__((ext_vector_type(4))) short s16x4;   // 8B store
typedef __attribute__((ext_vector_type(4))) float f4;      // MFMA C/D

__device__ __forceinline__ float bf2f(u16 h) {
  union { unsigned int u; float f; } c; c.u = ((unsigned int)h) << 16; return c.f;
}
__device__ __forceinline__ u16 f2bf(float f) {
  union { float f; unsigned int u; } c; c.f = f; unsigned int u = c.u;
  return (u16)((u + 0x7fffu + ((u >> 16) & 1u)) >> 16);
}
__device__ __forceinline__ int iclamp(int v, int lo, int hi) {
  return v < lo ? lo : (v > hi ? hi : v);
}
__device__ __forceinline__ void gload16(const void* g, void* l) {
  __builtin_amdgcn_global_load_lds(
      (const __attribute__((address_space(1))) void*)g,
      (__attribute__((address_space(3))) void*)l, 16, 0, 0);
}

// ---------------------------------------------------------------------------
__global__ __launch_bounds__(256) void scan_kernel(const int* __restrict__ mask,
                                                   int* __restrict__ pos) {
  __shared__ int part[256];
  int tid = threadIdx.x;
  int base = tid * 16, ssum = 0;
  for (int i = 0; i < 16; ++i) ssum += mask[base + i];
  part[tid] = ssum;
  __syncthreads();
  if (tid == 0) {
    int run = 0;
    for (int i = 0; i < 256; ++i) { int t = part[i]; part[i] = run; run += t; }
  }
  __syncthreads();
  int run = part[tid];
  for (int i = 0; i < 16; ++i) {
    int m = mask[base + i];
    run += m;
    pos[base + i] = run * m + 1;
  }
}

// ---------------------------------------------------------------------------
__device__ __forceinline__ void block_ln4(int row, f4 a, bool act,
    const float* __restrict__ s, const float* __restrict__ b,
    float* __restrict__ xo, u16* __restrict__ xh, float* red, int tid) {
  float s1 = 0.f, s2 = 0.f;
  if (act) {
#pragma unroll
    for (int j = 0; j < 4; ++j) { s1 += a[j]; s2 += a[j] * a[j]; }
  }
#pragma unroll
  for (int m = 1; m < 64; m <<= 1) { s1 += __shfl_xor(s1, m); s2 += __shfl_xor(s2, m); }
  if ((tid & 63) == 0) { red[tid >> 6] = s1; red[4 + (tid >> 6)] = s2; }
  __syncthreads();
  s1 = red[0] + red[1] + red[2] + red[3];
  s2 = red[4] + red[5] + red[6] + red[7];
  float mean = s1 * (1.f / DM);
  float var = s2 * (1.f / DM) - mean * mean;
  float inv = rsqrtf(var + 1e-5f);
  if (act) {
    const f4 sv = ((const f4*)s)[tid];
    const f4 bv = ((const f4*)b)[tid];
    f4 y;
    s16x4 hh;
#pragma unroll
    for (int j = 0; j < 4; ++j) {
      y[j] = (a[j] - mean) * inv * sv[j] + bv[j];
      hh[j] = (short)f2bf(y[j]);
    }
    ((f4*)xo)[(size_t)row * 192 + tid] = y;
    *(s16x4*)&xh[(size_t)row * DM + tid * 4] = hh;
  }
}

__global__ __launch_bounds__(256) void embed_kernel(const int* __restrict__ ids,
    const int* __restrict__ pos, const float* __restrict__ we,
    const float* __restrict__ pe, const float* __restrict__ te,
    const float* __restrict__ s, const float* __restrict__ b,
    float* __restrict__ xo, u16* __restrict__ xh) {
  __shared__ float red[8];
  int row = blockIdx.x, tid = threadIdx.x;
  bool act = tid < 192;
  f4 a = { 0.f, 0.f, 0.f, 0.f };
  if (act) {
    int id = ids[row], pz = pos[row];
    const f4 wv = ((const f4*)we)[(size_t)id * 192 + tid];
    const f4 pv = ((const f4*)pe)[(size_t)pz * 192 + tid];
    const f4 tv = ((const f4*)te)[tid];
#pragma unroll
    for (int j = 0; j < 4; ++j) a[j] = wv[j] + pv[j] + tv[j];
  }
  block_ln4(row, a, act, s, b, xo, xh, red, tid);
}

// in == xo allowed (in-place): each thread reads its own row slice before
// any write to the same slice.
__global__ __launch_bounds__(256) void ln_direct_kernel(
    const float* __restrict__ in, float* __restrict__ x, u16* __restrict__ xh,
    const float* __restrict__ s, const float* __restrict__ b) {
  __shared__ float red[8];
  int row = blockIdx.x, tid = threadIdx.x;
  bool act = tid < 192;
  f4 a = { 0.f, 0.f, 0.f, 0.f };
  if (act) a = ((const f4*)in)[(size_t)row * 192 + tid];
  block_ln4(row, a, act, s, b, x, xh, red, tid);
}

__global__ __launch_bounds__(256) void ln_fuse_kernel(
    const float* __restrict__ pp, int nparts, const float* __restrict__ bias,
    float* __restrict__ x, u16* __restrict__ xh,
    const float* __restrict__ s, const float* __restrict__ b) {
  __shared__ float red[8];
  int row = blockIdx.x, tid = threadIdx.x;
  bool act = tid < 192;
  f4 a = { 0.f, 0.f, 0.f, 0.f };
  if (act) {
    size_t i4 = (size_t)row * 192 + tid;
    a = ((const f4*)x)[i4];
    const f4 bb = ((const f4*)bias)[tid];
#pragma unroll
    for (int j = 0; j < 4; ++j) a[j] += bb[j];
    for (int p = 0; p < nparts; ++p) {
      const f4 pv = ((const f4*)pp)[(size_t)p * SQ * 192 + i4];
#pragma unroll
      for (int j = 0; j < 4; ++j) a[j] += pv[j];
    }
  }
  block_ln4(row, a, act, s, b, x, xh, red, tid);
}

// ---------------------------------------------------------------------------
// wconv v6: 128(K)x64(N) region per block as two 64x64 sub-tiles.
__global__ __launch_bounds__(256) void wconv_all(
    const float* __restrict__ wq, const float* __restrict__ wk,
    const float* __restrict__ wv, const float* __restrict__ wo,
    const float* __restrict__ w1, const float* __restrict__ w2,
    u16* __restrict__ Wqkv, u16* __restrict__ Wo,
    u16* __restrict__ W1, u16* __restrict__ W2) {
  __shared__ float t[64 * 65];
  int b = blockIdx.x;
  int lay = blockIdx.y;
  const float* src;
  u16* dst;
  int K, N, rowoff, nx, tile;
  if (b < 216) {
    int j = b / 72;
    tile = b - j * 72;
    src = ((j == 0) ? wq : ((j == 1) ? wk : wv)) + (size_t)lay * DM * DM;
    dst = Wqkv + (size_t)lay * 3 * DM * DM;
    K = DM; N = DM; rowoff = j * DM; nx = 12;
  } else if (b < 288) {
    tile = b - 216;
    src = wo + (size_t)lay * DM * DM; dst = Wo + (size_t)lay * DM * DM;
    K = DM; N = DM; rowoff = 0; nx = 12;
  } else if (b < 576) {
    tile = b - 288;
    src = w1 + (size_t)lay * DM * FF; dst = W1 + (size_t)lay * DM * FF;
    K = DM; N = FF; rowoff = 0; nx = 48;
  } else {
    tile = b - 576;
    src = w2 + (size_t)lay * FF * DM; dst = W2 + (size_t)lay * FF * DM;
    K = FF; N = DM; rowoff = 0; nx = 12;
  }
  int n0 = (tile % nx) * 64, k0 = (tile / nx) * 128;   // 128 k-rows per block
  int tid = threadIdx.x;
  int q = tid & 15, kr = tid >> 4;  // kr 0..15

  // issue ALL 8 loads first (two sub-tiles); v1 stays in regs during tile0
  f4 v0[4], v1[4];
#pragma unroll
  for (int p = 0; p < 4; ++p)
    v0[p] = *(const f4*)&src[(size_t)(k0 + kr + p * 16) * N + n0 + q * 4];
#pragma unroll
  for (int p = 0; p < 4; ++p)
    v1[p] = *(const f4*)&src[(size_t)(k0 + 64 + kr + p * 16) * N + n0 + q * 4];

  // ---- sub-tile 0
#pragma unroll
  for (int p = 0; p < 4; ++p) {
    int k = kr + p * 16;
#pragma unroll
    for (int j = 0; j < 4; ++j) t[k * 65 + q * 4 + j] = v0[p][j];
  }
  __syncthreads();
  {
    int n = tid >> 4, kq = (tid & 15) * 4;
#pragma unroll
    for (int c = 0; c < 4; ++c) {
      int nn = n + c * 16;
      s16x4 st;
#pragma unroll
      for (int i = 0; i < 4; ++i)
        st[i] = (short)f2bf(t[(kq + i) * 65 + nn]);
      *(s16x4*)&dst[(size_t)(rowoff + n0 + nn) * K + k0 + kq] = st;
    }
  }
  __syncthreads();
  // ---- sub-tile 1
#pragma unroll
  for (int p = 0; p < 4; ++p) {
    int k = kr + p * 16;
#pragma unroll
    for (int j = 0; j < 4; ++j) t[k * 65 + q * 4 + j] = v1[p][j];
  }
  __syncthreads();
  {
    int n = tid >> 4, kq = (tid & 15) * 4;
#pragma unroll
    for (int c = 0; c < 4; ++c) {
      int nn = n + c * 16;
      s16x4 st;
#pragma unroll
      for (int i = 0; i < 4; ++i)
        st[i] = (short)f2bf(t[(kq + i) * 65 + nn]);
      *(s16x4*)&dst[(size_t)(rowoff + n0 + nn) * K + k0 + 64 + kq] = st;
    }
  }
}

// ---------------------------------------------------------------------------
// bf16 GEMM, 128x64 tile, BK=64, 4 waves (2x2, each 64x32), 3 blocks/CU.
// EPI 3: f32 partial; EPI 4: in-place +bias+resid (outf read-modify-write).
template <int EPI>
__global__ __launch_bounds__(256, 3) void gemm1(
    const u16* __restrict__ A, const u16* __restrict__ B, int Kld, int ksl,
    int nx, int ntiles,
    const float* __restrict__ bias0,
    float* __restrict__ outf) {
  __shared__ __align__(16) char smem[49152];

  const int tid = threadIdx.x;
  const int l = tid & 63;
  const int w = tid >> 6;
  const int lr = l & 15;
  const int lg = l >> 4;
  const int nwg = gridDim.x;
  const int bid = blockIdx.x;
  const int wg = (bid & 7) * (nwg >> 3) + (bid >> 3);
  const int part = wg / ntiles;
  const int t = wg - part * ntiles;
  const int bm = (t / nx) * 128;
  const int bn = (t % nx) * 64;
  const int k0 = part * ksl;
  const int wr = (w >> 1) * 64;
  const int wc = (w & 1) * 32;

  f4 acc[4][2];
  f4 z = { 0.f, 0.f, 0.f, 0.f };
#pragma unroll
  for (int i = 0; i < 4; ++i)
#pragma unroll
    for (int j = 0; j < 2; ++j) acc[i][j] = z;

  const int srow = tid >> 3;                            // 32 rows / stage call
  const int scol = ((tid & 7) * 8) ^ ((srow & 7) * 8);  // pre-swizzled source
  const int xw = (lr & 7) * 8;                          // read-side XOR

  const int nkt = ksl >> 6;

  auto stage = [&](int slot, int kt) {
    int ksrc = k0 + (kt << 6);
    char* la = smem + slot * 24576 + (size_t)(tid & ~63) * 16;
    char* lb = la + 16384;
#pragma unroll
    for (int r = 0; r < 4; ++r)
      gload16(A + (size_t)(bm + srow + r * 32) * Kld + ksrc + scol, la + r * 4096);
#pragma unroll
    for (int r = 0; r < 2; ++r)
      gload16(B + (size_t)(bn + srow + r * 32) * Kld + ksrc + scol, lb + r * 4096);
  };

  stage(0, 0);
  stage(1, 1);
  asm volatile("s_waitcnt vmcnt(6)" ::: "memory");
  __builtin_amdgcn_s_barrier();
  __builtin_amdgcn_sched_barrier(0);

  for (int kt = 0; kt < nkt; ++kt) {
    const int cur = kt & 1;
    const u16* sA = (const u16*)(smem + cur * 24576);
    const u16* sB = sA + 8192;
#pragma unroll
    for (int ks = 0; ks < 2; ++ks) {
      bf8_t af[4], bfr[2];
#pragma unroll
      for (int mt = 0; mt < 4; ++mt)
        af[mt] = *(const bf8_t*)&sA[(wr + mt * 16 + lr) * 64 + ((ks * 32 + lg * 8) ^ xw)];
#pragma unroll
      for (int nt = 0; nt < 2; ++nt)
        bfr[nt] = *(const bf8_t*)&sB[(wc + nt * 16 + lr) * 64 + ((ks * 32 + lg * 8) ^ xw)];
#pragma unroll
      for (int mt = 0; mt < 4; ++mt)
#pragma unroll
        for (int nt = 0; nt < 2; ++nt)
          acc[mt][nt] = __builtin_amdgcn_mfma_f32_16x16x32_bf16(af[mt], bfr[nt], acc[mt][nt], 0, 0, 0);
    }
    asm volatile("s_waitcnt lgkmcnt(0)" ::: "memory");
    __builtin_amdgcn_sched_barrier(0);
    __builtin_amdgcn_s_barrier();  // block-wide reads of slot cur done
    if (kt + 2 < nkt) {
      stage(cur, kt + 2);
      asm volatile("s_waitcnt vmcnt(6)" ::: "memory");  // tile kt+1 landed
    } else {
      asm volatile("s_waitcnt vmcnt(0)" ::: "memory");
    }
    __builtin_amdgcn_s_barrier();  // publish tile kt+1
    __builtin_amdgcn_sched_barrier(0);
  }
  __syncthreads();

#pragma unroll
  for (int mt = 0; mt < 4; ++mt)
#pragma unroll
    for (int nt = 0; nt < 2; ++nt) {
      int colg = bn + wc + nt * 16 + lr;
#pragma unroll
      for (int r = 0; r < 4; ++r) {
        int rowg = bm + wr + mt * 16 + lg * 4 + r;
        size_t idx = (size_t)rowg * DM + colg;
        if constexpr (EPI == 3) {
          outf[(size_t)part * SQ * DM + idx] = acc[mt][nt][r];
        } else {
          // in-place: x[idx] = gemm + bias + x[idx]; each idx owned by one
          // thread, read precedes write on the same address.
          outf[idx] = acc[mt][nt][r] + bias0[colg] + outf[idx];
        }
      }
    }
}

// ---------------------------------------------------------------------------
// gemm2: m97-style 128x128 tile, BK=64, single-buffered 32KB LDS,
// 2 barriers/kt, 4 waves (2x2, each 64x64, acc[4][4]), 3 blocks/CU.
// EPI 0: qkv scatter; EPI 2: gelu->bf16; EPI 3: f32 split-K partial.
template <int EPI>
__global__ __launch_bounds__(256, 3) void gemm2(
    const u16* __restrict__ A, const u16* __restrict__ B, int Kld, int ksl,
    int nx, int ntiles,
    const float* __restrict__ bias0, const float* __restrict__ bias1,
    const float* __restrict__ bias2,
    u16* __restrict__ oh, u16* __restrict__ Qb, u16* __restrict__ Kb,
    u16* __restrict__ VTb, float* __restrict__ outf) {
  // K-loop: A 16KB + B 16KB = 32KB. Epilogue repack: 4 waves x 9216B = 36KB.
  __shared__ __align__(16) char smem[36864];

  const int tid = threadIdx.x;
  const int l = tid & 63;
  const int w = tid >> 6;
  const int lr = l & 15;
  const int lg = l >> 4;
  const int nwg = gridDim.x;
  const int bid = blockIdx.x;
  const int wg = (bid & 7) * (nwg >> 3) + (bid >> 3);
  const int part = wg / ntiles;
  const int t = wg - part * ntiles;
  const int bm = (t / nx) * 128;
  const int bn = (t % nx) * 128;
  const int k0 = part * ksl;
  const int wr = (w >> 1) * 64;
  const int wc = (w & 1) * 64;

  f4 acc[4][4];
  f4 z = { 0.f, 0.f, 0.f, 0.f };
#pragma unroll
  for (int i = 0; i < 4; ++i)
#pragma unroll
    for (int j = 0; j < 4; ++j) acc[i][j] = z;

  const int srow = tid >> 3;                            // 32 rows / stage call
  const int scol = ((tid & 7) * 8) ^ ((srow & 7) * 8);  // pre-swizzled source
  const int xw = (lr & 7) * 8;                          // read-side XOR

  const int nkt = ksl >> 6;

  auto stage = [&](int kt) {
    int ksrc = k0 + (kt << 6);
    char* la = smem + (size_t)(tid & ~63) * 16;
    char* lb = la + 16384;
#pragma unroll
    for (int r = 0; r < 4; ++r)
      gload16(A + (size_t)(bm + srow + r * 32) * Kld + ksrc + scol, la + r * 4096);
#pragma unroll
    for (int r = 0; r < 4; ++r)
      gload16(B + (size_t)(bn + srow + r * 32) * Kld + ksrc + scol, lb + r * 4096);
  };

  stage(0);
  for (int kt = 0; kt < nkt; ++kt) {
    asm volatile("s_waitcnt vmcnt(0)" ::: "memory");
    __builtin_amdgcn_s_barrier();          // staged tile visible to all waves
    __builtin_amdgcn_sched_barrier(0);
    const u16* sA = (const u16*)smem;
    const u16* sB = sA + 8192;
#pragma unroll
    for (int ks = 0; ks < 2; ++ks) {
      bf8_t af[4], bfr[4];
#pragma unroll
      for (int mt = 0; mt < 4; ++mt)
        af[mt] = *(const bf8_t*)&sA[(wr + mt * 16 + lr) * 64 + ((ks * 32 + lg * 8) ^ xw)];
#pragma unroll
      for (int nt = 0; nt < 4; ++nt)
        bfr[nt] = *(const bf8_t*)&sB[(wc + nt * 16 + lr) * 64 + ((ks * 32 + lg * 8) ^ xw)];
#pragma unroll
      for (int mt = 0; mt < 4; ++mt)
#pragma unroll
        for (int nt = 0; nt < 4; ++nt)
          acc[mt][nt] = __builtin_amdgcn_mfma_f32_16x16x32_bf16(af[mt], bfr[nt], acc[mt][nt], 0, 0, 0);
    }
    asm volatile("s_waitcnt lgkmcnt(0)" ::: "memory");
    __builtin_amdgcn_sched_barrier(0);
    __builtin_amdgcn_s_barrier();          // all reads done; buffer reusable
    if (kt + 1 < nkt) stage(kt + 1);       // overlaps other blocks' compute
  }

  if constexpr (EPI == 3) {
    // direct f32 split-K partial stores (no repack)
#pragma unroll
    for (int mt = 0; mt < 4; ++mt)
#pragma unroll
      for (int nt = 0; nt < 4; ++nt) {
        int colg = bn + wc + nt * 16 + lr;
#pragma unroll
        for (int r = 0; r < 4; ++r) {
          int rowg = bm + wr + mt * 16 + lg * 4 + r;
          outf[(size_t)part * SQ * DM + (size_t)rowg * DM + colg] = acc[mt][nt][r];
        }
      }
    return;
  }

  // ---- epilogues. Per-wave LDS [64][36] f32, two 32-col half-passes.
  float* ep = (float*)(smem + w * 9216);
  const int nbase = bn + wc;               // multiple of 64

  if constexpr (EPI == 0) {
    int tgt = nbase / DM;                  // 0=q 1=k 2=v (64-granules don't straddle)
    int within = nbase - tgt * DM;         // multiple of 64
    int head = within >> 6;
    const float* bp = (tgt == 0) ? bias0 : ((tgt == 1) ? bias1 : bias2);
    if (tgt == 2) {
      // direct from acc -> VT[H][DH][S]
#pragma unroll
      for (int mt = 0; mt < 4; ++mt)
#pragma unroll
        for (int nt = 0; nt < 4; ++nt) {
          int dh = nt * 16 + lr;
          float bb = bp[within + dh];
          int s0 = bm + wr + mt * 16 + lg * 4;
          s16x4 st;
#pragma unroll
          for (int r = 0; r < 4; ++r) st[r] = (short)f2bf(acc[mt][nt][r] + bb);
          *(s16x4*)&VTb[((size_t)(head * DHD + dh)) * SQ + s0] = st;
        }
    } else {
      u16* dst = (tgt == 0) ? Qb : Kb;
      float scale = (tgt == 0) ? 0.125f : 1.0f;
      int coloff = (l & 7) * 4;
#pragma unroll
      for (int half = 0; half < 2; ++half) {
        if (half) asm volatile("s_waitcnt lgkmcnt(0)" ::: "memory");
#pragma unroll
        for (int mt = 0; mt < 4; ++mt)
#pragma unroll
          for (int n2 = 0; n2 < 2; ++n2)
#pragma unroll
            for (int r = 0; r < 4; ++r)
              ep[(mt * 16 + lg * 4 + r) * 36 + n2 * 16 + lr] = acc[mt][half * 2 + n2][r];
        asm volatile("s_waitcnt lgkmcnt(0)" ::: "memory");
#pragma unroll
        for (int i = 0; i < 8; ++i) {
          int row = (l >> 3) + i * 8;
          int gs = bm + wr + row;
          f4 v = *(f4*)&ep[row * 36 + coloff];
          s16x4 st;
#pragma unroll
          for (int j = 0; j < 4; ++j)
            st[j] = (short)f2bf((v[j] + bp[within + half * 32 + coloff + j]) * scale);
          *(s16x4*)&dst[((size_t)head * SQ + gs) * DHD + half * 32 + coloff] = st;
        }
      }
    }
  } else {  // EPI == 2: gelu -> bf16 [S][FF]
    int coloff = (l & 7) * 4;
#pragma unroll
    for (int half = 0; half < 2; ++half) {
      if (half) asm volatile("s_waitcnt lgkmcnt(0)" ::: "memory");
#pragma unroll
      for (int mt = 0; mt < 4; ++mt)
#pragma unroll
        for (int n2 = 0; n2 < 2; ++n2)
#pragma unroll
          for (int r = 0; r < 4; ++r)
            ep[(mt * 16 + lg * 4 + r) * 36 + n2 * 16 + lr] = acc[mt][half * 2 + n2][r];
      asm volatile("s_waitcnt lgkmcnt(0)" ::: "memory");
#pragma unroll
      for (int i = 0; i < 8; ++i) {
        int row = (l >> 3) + i * 8;
        int gs = bm + wr + row;
        f4 v = *(f4*)&ep[row * 36 + coloff];
        s16x4 hi;
#pragma unroll
        for (int j = 0; j < 4; ++j) {
          float t2 = v[j] + bias0[nbase + half * 32 + coloff + j];
          t2 = 0.5f * t2 * (1.f + erff(t2 * 0.70710678118654752f));  // exact gelu
          hi[j] = (short)f2bf(t2);
        }
        *(s16x4*)&oh[(size_t)gs * FF + nbase + half * 32 + coloff] = hi;
      }
    }
  }
}

// ---------------------------------------------------------------------------
// sliding-window attention (R11 structure): 2 waves/block, each wave owns 32
// queries end-to-end (independent online softmax, no merge). grid (SQ/64, NH).
// XCD swizzle — 768 blocks = 8 XCDs x 96 ids.
__global__ __launch_bounds__(128) void attn_kernel(
    const u16* __restrict__ Qb, const u16* __restrict__ Kb,
    const u16* __restrict__ VTb, const int* __restrict__ mask,
    u16* __restrict__ ah) {
  __shared__ __align__(16) u16 Pl[2][32 * 72];
  __shared__ float mwin[640];
  const int tid = threadIdx.x;
  const int w = tid >> 6;          // wave id 0/1
  const int l = tid & 63;
  const int lr = l & 15, lg = l >> 4;
  // XCD swizzle: dispatch index lin -> id so each XCD gets 96 consecutive ids
  const int lin = blockIdx.y * 64 + blockIdx.x;       // == dispatch order
  const int id = (lin & 7) * 96 + (lin >> 3);         // bijective, 768 = 8*96
  const int h = id >> 6;
  const int q0 = (id & 63) * 64;
  const int qw = q0 + w * 32;      // this wave's first query
  const int kbw = qw - 256;        // this wave's key-window base
  for (int i = tid; i < 640; i += 128) {
    int kg = q0 - 256 + i;
    mwin[i] = (kg >= 0 && kg < SQ && mask[kg] != 0) ? 1.f : 0.f;
  }
  __syncthreads();
  u16* Plw = Pl[w];

  bf8_t qf[2][2];
#pragma unroll
  for (int mt = 0; mt < 2; ++mt)
#pragma unroll
    for (int ks = 0; ks < 2; ++ks)
      qf[mt][ks] = *(const bf8_t*)&Qb[((size_t)h * SQ + qw + mt * 16 + lr) * DHD + ks * 32 + lg * 8];

  f4 o[2][4];
  f4 z = { 0.f, 0.f, 0.f, 0.f };
  float mrow[2][4], lrow[2][4];
#pragma unroll
  for (int mt = 0; mt < 2; ++mt)
#pragma unroll
    for (int nt = 0; nt < 4; ++nt) o[mt][nt] = z;
#pragma unroll
  for (int mt = 0; mt < 2; ++mt)
#pragma unroll
    for (int r = 0; r < 4; ++r) { mrow[mt][r] = -1e30f; lrow[mt][r] = 0.f; }

  for (int kc = 0; kc < 9; ++kc) {
    int klb = kc * 64;             // wave-relative chunk base
    int mo = w * 32 + klb;         // block-mwin offset of this chunk
    f4 sc[2][4];
#pragma unroll
    for (int mt = 0; mt < 2; ++mt)
#pragma unroll
      for (int nt = 0; nt < 4; ++nt) sc[mt][nt] = z;
#pragma unroll
    for (int ks = 0; ks < 2; ++ks) {
      bf8_t kf[4];
#pragma unroll
      for (int nt = 0; nt < 4; ++nt) {
        int krow = iclamp(kbw + klb + nt * 16 + lr, 0, SQ - 1);
        kf[nt] = *(const bf8_t*)&Kb[((size_t)h * SQ + krow) * DHD + ks * 32 + lg * 8];
      }
#pragma unroll
      for (int mt = 0; mt < 2; ++mt)
#pragma unroll
        for (int nt = 0; nt < 4; ++nt)
          sc[mt][nt] = __builtin_amdgcn_mfma_f32_16x16x32_bf16(qf[mt][ks], kf[nt], sc[mt][nt], 0, 0, 0);
    }
    bool edge = (kc == 0) | (kc == 8);
    // interior chunks fully in-band; only key validity can mask.
    unsigned long long vb = __ballot(mwin[mo + l] > 0.5f);
    if (edge || vb != ~0ull) {
#pragma unroll
      for (int mt = 0; mt < 2; ++mt)
#pragma unroll
        for (int nt = 0; nt < 4; ++nt) {
          int col = nt * 16 + lr;
          int kg = kbw + klb + col;
          float mk = mwin[mo + col];
#pragma unroll
          for (int r = 0; r < 4; ++r) {
            int qg = qw + mt * 16 + lg * 4 + r;
            int d = kg - qg;
            bool ok = (mk > 0.5f) && (!edge || ((d <= WW) && (d >= -WW)));
            sc[mt][nt][r] = ok ? sc[mt][nt][r] : -3.0e38f;
          }
        }
    }
#pragma unroll
    for (int mt = 0; mt < 2; ++mt)
#pragma unroll
      for (int r = 0; r < 4; ++r) {
        float cm = fmaxf(fmaxf(sc[mt][0][r], sc[mt][1][r]),
                         fmaxf(sc[mt][2][r], sc[mt][3][r]));
#pragma unroll
        for (int m2 = 1; m2 < 16; m2 <<= 1) cm = fmaxf(cm, __shfl_xor(cm, m2));
        float mn = fmaxf(fmaxf(mrow[mt][r], cm), -1e30f);
        float scl = __expf(mrow[mt][r] - mn);
        mrow[mt][r] = mn;
        float ps = 0.f;
#pragma unroll
        for (int nt = 0; nt < 4; ++nt) {
          float pv = __expf(sc[mt][nt][r] - mn);
          sc[mt][nt][r] = pv;
          ps += pv;
        }
#pragma unroll
        for (int m2 = 1; m2 < 16; m2 <<= 1) ps += __shfl_xor(ps, m2);
        lrow[mt][r] = lrow[mt][r] * scl + ps;
#pragma unroll
        for (int nt = 0; nt < 4; ++nt) o[mt][nt][r] *= scl;
#pragma unroll
        for (int nt = 0; nt < 4; ++nt)
          Plw[(mt * 16 + lg * 4 + r) * 72 + nt * 16 + lr] = f2bf(sc[mt][nt][r]);
      }
    asm volatile("s_waitcnt lgkmcnt(0)" ::: "memory");
#pragma unroll
    for (int ks = 0; ks < 2; ++ks) {
      bf8_t pa[2], vf[4];
#pragma unroll
      for (int mt = 0; mt < 2; ++mt)
        pa[mt] = *(const bf8_t*)&Plw[(mt * 16 + lr) * 72 + ks * 32 + lg * 8];
      int kbase = iclamp(kbw + klb + ks * 32 + lg * 8, 0, SQ - 8);
#pragma unroll
      for (int nt = 0; nt < 4; ++nt)
        vf[nt] = *(const bf8_t*)&VTb[((size_t)h * DHD + nt * 16 + lr) * SQ + kbase];
#pragma unroll
      for (int mt = 0; mt < 2; ++mt)
#pragma unroll
        for (int nt = 0; nt < 4; ++nt)
          o[mt][nt] = __builtin_amdgcn_mfma_f32_16x16x32_bf16(pa[mt], vf[nt], o[mt][nt], 0, 0, 0);
    }
  }
#pragma unroll
  for (int mt = 0; mt < 2; ++mt)
#pragma unroll
    for (int nt = 0; nt < 4; ++nt) {
      int col = h * DHD + nt * 16 + lr;
#pragma unroll
      for (int r = 0; r < 4; ++r) {
        int gq = qw + mt * 16 + lg * 4 + r;
        float v = o[mt][nt][r] / lrow[mt][r];
        ah[(size_t)gq * DM + col] = f2bf(v);
      }
    }
}

// ---------------------------------------------------------------------------
__global__ __launch_bounds__(256) void head1_kernel(const float* __restrict__ x,
    const float* __restrict__ wp, const float* __restrict__ bp,
    float* __restrict__ y) {
  __shared__ float x0[DM];
  __shared__ float part[4][64];
  int tid = threadIdx.x;
  int w = tid >> 6, l = tid & 63;
  for (int i = tid; i < DM; i += 256) x0[i] = x[i];
  __syncthreads();
  int j = blockIdx.x * 64 + l;
  float a = 0.f;
  int i0 = w * 192;
#pragma unroll 4
  for (int i = i0; i < i0 + 192; ++i) a += x0[i] * wp[(size_t)i * DM + j];
  part[w][l] = a;
  __syncthreads();
  if (w == 0) {
    float t = part[0][l] + part[1][l] + part[2][l] + part[3][l] + bp[j];
    y[j] = tanhf(t);
  }
}

__global__ __launch_bounds__(64) void head2_kernel(const float* __restrict__ y,
    const float* __restrict__ wc, const float* __restrict__ bc,
    float* __restrict__ out) {
  int l = threadIdx.x;
  float acc[6] = {0.f, 0.f, 0.f, 0.f, 0.f, 0.f};
  for (int i = l; i < DM; i += 64) {
    float yv = y[i];
#pragma unroll
    for (int j = 0; j < 6; ++j) acc[j] += yv * wc[i * 6 + j];
  }
#pragma unroll
  for (int j = 0; j < 6; ++j)
#pragma unroll
    for (int m = 1; m < 64; m <<= 1) acc[j] += __shfl_xor(acc[j], m);
  if (l == 0) {
#pragma unroll
    for (int j = 0; j < 6; ++j) out[j] = acc[j] + bc[j];
  }
}

// ---------------------------------------------------------------------------
extern "C" void kernel_launch(void* const* d_in, const int* in_sizes, int n_in,
                              void* d_out, int out_size, void* d_ws, size_t ws_size,
                              hipStream_t stream) {
  const int* ids = (const int*)d_in[0];
  const int* mask = (const int*)d_in[1];
  const float* we = (const float*)d_in[2];
  const float* pe = (const float*)d_in[3];
  const float* te = (const float*)d_in[4];
  const float* ln_e_s = (const float*)d_in[5];
  const float* ln_e_b = (const float*)d_in[6];
  const float* wq = (const float*)d_in[7];
  const float* bq = (const float*)d_in[8];
  const float* wk = (const float*)d_in[9];
  const float* bk = (const float*)d_in[10];
  const float* wv = (const float*)d_in[11];
  const float* bv = (const float*)d_in[12];
  const float* wo = (const float*)d_in[13];
  const float* bo = (const float*)d_in[14];
  const float* ln1_s = (const float*)d_in[15];
  const float* ln1_b = (const float*)d_in[16];
  const float* w1 = (const float*)d_in[17];
  const float* b1 = (const float*)d_in[18];
  const float* w2 = (const float*)d_in[19];
  const float* b2 = (const float*)d_in[20];
  const float* ln2_s = (const float*)d_in[21];
  const float* ln2_b = (const float*)d_in[22];
  const float* wpool = (const float*)d_in[23];
  const float* bpool = (const float*)d_in[24];
  const float* wcls = (const float*)d_in[25];
  const float* bcls = (const float*)d_in[26];

  char* p = (char*)d_ws;
  auto take = [&](size_t bytes) {
    char* r = p;
    p += (bytes + 255) & ~(size_t)255;
    return r;
  };
  int* pos = (int*)take((size_t)SQ * 4);
  float* x = (float*)take((size_t)SQ * DM * 4);
  float* pp = (float*)take((size_t)4 * SQ * DM * 4);  // split-K partials (<=4)
  u16* xh = (u16*)take((size_t)SQ * DM * 2);
  u16* Wqkv_h = (u16*)take((size_t)NL * 3 * DM * DM * 2);
  u16* Wo_h = (u16*)take((size_t)NL * DM * DM * 2);
  u16* W1_h = (u16*)take((size_t)NL * DM * FF * 2);
  u16* W2_h = (u16*)take((size_t)NL * FF * DM * 2);
  u16* Qb = (u16*)take((size_t)NH * SQ * DHD * 2);
  u16* Kbf = (u16*)take((size_t)NH * SQ * DHD * 2);
  u16* VTb = (u16*)take((size_t)NH * DHD * SQ * 2);
  u16* ah_ = (u16*)take((size_t)SQ * DM * 2);
  u16* hh = (u16*)take((size_t)SQ * FF * 2);
  float* ypool = (float*)take((size_t)DM * 4);

  scan_kernel<<<dim3(1), dim3(256), 0, stream>>>(mask, pos);
  embed_kernel<<<dim3(SQ), dim3(256), 0, stream>>>(ids, pos, we, pe, te, ln_e_s, ln_e_b, x, xh);
  wconv_all<<<dim3(864, NL), dim3(256), 0, stream>>>(
      wq, wk, wv, wo, w1, w2, Wqkv_h, Wo_h, W1_h, W2_h);

  for (int l = 0; l < NL; ++l) {
    const u16* Wq_l = Wqkv_h + (size_t)l * 3 * DM * DM;
    const u16* Wo_l = Wo_h + (size_t)l * DM * DM;
    const u16* W1_l = W1_h + (size_t)l * DM * FF;
    const u16* W2_l = W2_h + (size_t)l * FF * DM;

    // qkv: M=4096 N=2304 K=768, 128x128 tile -> 32x18 = 576 blocks
    gemm2<0><<<dim3(576), dim3(256), 0, stream>>>(
        xh, Wq_l, DM, DM, 18, 576, bq + (size_t)l * DM, bk + (size_t)l * DM,
        bv + (size_t)l * DM, nullptr, Qb, Kbf, VTb, nullptr);
    attn_kernel<<<dim3(SQ / 64, NH), dim3(128), 0, stream>>>(Qb, Kbf, VTb, mask, ah_);
    // o-proj: M=4096 N=768 K=768, 128x64 tile, in-place x += gemm+bias
    gemm1<4><<<dim3(384), dim3(256), 0, stream>>>(
        ah_, Wo_l, DM, DM, 12, 384, bo + (size_t)l * DM, x);
    ln_direct_kernel<<<dim3(SQ), dim3(256), 0, stream>>>(
        x, x, xh, ln1_s + (size_t)l * DM, ln1_b + (size_t)l * DM);
    // ffn1: M=4096 N=3072 K=768, 128x128 tile -> 32x24 = 768 blocks (1 pass)
    gemm2<2><<<dim3(768), dim3(256), 0, stream>>>(
        xh, W1_l, DM, DM, 24, 768, b1 + (size_t)l * FF, nullptr, nullptr,
        hh, nullptr, nullptr, nullptr, nullptr);
    // ffn2: M=4096 N=768 K=3072, 128x128 tile, split-K 4 -> 192x4 = 768
    // blocks of 12 kt (exactly 1.0 pass)
    gemm2<3><<<dim3(768), dim3(256), 0, stream>>>(
        hh, W2_l, FF, FF / 4, 6, 192, nullptr, nullptr, nullptr,
        nullptr, nullptr, nullptr, nullptr, pp);
    ln_fuse_kernel<<<dim3(SQ), dim3(256), 0, stream>>>(
        pp, 4, b2 + (size_t)l * DM, x, xh, ln2_s + (size_t)l * DM, ln2_b + (size_t)l * DM);
  }

  head1_kernel<<<dim3(12), dim3(256), 0, stream>>>(x, wpool, bpool, ypool);
  head2_kernel<<<dim3(1), dim3(64), 0, stream>>>(ypool, wcls, bcls, (float*)d_out);
}